// Round 1
// baseline (1679.984 us; speedup 1.0000x reference)
//
#include <hip/hip_runtime.h>
#include <hip/hip_bf16.h>
#include <limits.h>

#define NSEG 200
#define STRENGTH 1e-3f

__device__ __forceinline__ int bucket_of(float x, int B, float scale) {
    float t = (x + 6.0f) * scale;   // scale = B/12
    int b = (int)floorf(t);
    b = b < 0 ? 0 : (b > B - 1 ? B - 1 : b);
    return b;
}

// ---- 1. histogram of (segment, bucket) ----
__global__ void k_hist(const float* __restrict__ x, const int* __restrict__ seg,
                       int* __restrict__ counts, int N, int B, float scale) {
    int stride = gridDim.x * blockDim.x;
    for (int i = blockIdx.x * blockDim.x + threadIdx.x; i < N; i += stride) {
        int s = seg[i];
        int b = bucket_of(x[i], B, scale);
        atomicAdd(&counts[s * B + b], 1);
    }
}

// ---- 2. exclusive scan over M = NSEG*B counters (3 kernels, TILE=2048) ----
__global__ void k_scan_partial(const int* __restrict__ counts, int* __restrict__ partials, int M) {
    __shared__ int sdata[256];
    int base = blockIdx.x * 2048;
    int sum = 0;
    for (int k = threadIdx.x; k < 2048; k += 256) {
        int idx = base + k;
        sum += (idx < M) ? counts[idx] : 0;
    }
    sdata[threadIdx.x] = sum;
    __syncthreads();
    for (int off = 128; off > 0; off >>= 1) {
        if (threadIdx.x < off) sdata[threadIdx.x] += sdata[threadIdx.x + off];
        __syncthreads();
    }
    if (threadIdx.x == 0) partials[blockIdx.x] = sdata[0];
}

__global__ void k_scan_carry(int* __restrict__ partials, int nb) {
    __shared__ int bufA[1024], bufB[1024];
    int t = threadIdx.x;
    int v = (t < nb) ? partials[t] : 0;
    int* src = bufA; int* dst = bufB;
    src[t] = v;
    __syncthreads();
    for (int off = 1; off < 1024; off <<= 1) {
        dst[t] = src[t] + ((t >= off) ? src[t - off] : 0);
        __syncthreads();
        int* tmp = src; src = dst; dst = tmp;
    }
    if (t < nb) partials[t] = src[t] - v;   // exclusive
}

__global__ void k_scan_final(const int* __restrict__ counts, const int* __restrict__ partials,
                             int* __restrict__ cursor, int M) {
    __shared__ int tile[2048];
    __shared__ int sa[256], sb[256];
    int t = threadIdx.x;
    int base = blockIdx.x * 2048;
    for (int k = t; k < 2048; k += 256) {
        int idx = base + k;
        tile[k] = (idx < M) ? counts[idx] : 0;
    }
    __syncthreads();
    int loc[8]; int run = 0;
    for (int k = 0; k < 8; ++k) { loc[k] = run; run += tile[t * 8 + k]; }
    int v = run;
    int* src = sa; int* dst = sb;
    src[t] = v;
    __syncthreads();
    for (int off = 1; off < 256; off <<= 1) {
        dst[t] = src[t] + ((t >= off) ? src[t - off] : 0);
        __syncthreads();
        int* tmp = src; src = dst; dst = tmp;
    }
    int texcl = src[t] - v;
    int gbase = partials[blockIdx.x];
    for (int k = 0; k < 8; ++k) {
        int idx = base + t * 8 + k;
        if (idx < M) cursor[idx] = gbase + texcl + loc[k];
    }
}

// ---- 3. scatter into bucket-grouped order (non-stable; cursor becomes "ends") ----
__global__ void k_scatter(const float* __restrict__ x, const int* __restrict__ seg,
                          int* __restrict__ cursor, float* __restrict__ sx,
                          int N, int B, float scale) {
    int stride = gridDim.x * blockDim.x;
    for (int i = blockIdx.x * blockDim.x + threadIdx.x; i < N; i += stride) {
        float v = x[i];
        int g = seg[i] * B + bucket_of(v, B, scale);
        int pos = atomicAdd(&cursor[g], 1);
        sx[pos] = v;
    }
}

// ---- 4. rank within bucket -> exact sorted position -> |diff|, per-segment sums ----
__global__ void k_emd(const float* __restrict__ sx, const float* __restrict__ y,
                      const int* __restrict__ seg, const int* __restrict__ ends,
                      float* __restrict__ segSums, int N, int B, float scale) {
    int p = blockIdx.x * blockDim.x + threadIdx.x;
    float diff = 0.f;
    int s = INT_MAX;
    if (p < N) {
        float v = sx[p];
        s = seg[p];                       // permutation preserves segment ranges
        int g = s * B + bucket_of(v, B, scale);
        int start = (g == 0) ? 0 : ends[g - 1];
        int end = ends[g];
        int rank = 0;
        for (int j = start; j < end; ++j) {
            float vj = sx[j];
            rank += (vj < v) || (vj == v && j < p);
        }
        diff = fabsf(v - y[start + rank]);
    }
    // wave-level reduction keyed by segment (waves span >1 segment only at boundaries)
    int smin = s;
    for (int off = 32; off > 0; off >>= 1) smin = min(smin, __shfl_xor(smin, off));
    float part = (s == smin) ? diff : 0.f;
    for (int off = 32; off > 0; off >>= 1) part += __shfl_xor(part, off);
    int lane = threadIdx.x & 63;
    if (lane == 0 && smin != INT_MAX) atomicAdd(&segSums[smin], part);
    if (s != smin && s != INT_MAX) atomicAdd(&segSums[s], diff);
}

// ---- 5. finalize: mean over segments of (sum/count) * strength ----
__global__ void k_final(const float* __restrict__ segSums, const int* __restrict__ ends,
                        float* __restrict__ out, int B) {
    __shared__ float red[256];
    int t = threadIdx.x;
    float acc = 0.f;
    for (int s = t; s < NSEG; s += 256) {
        int end = ends[(s + 1) * B - 1];
        int st = (s == 0) ? 0 : ends[s * B - 1];
        float cnt = (float)(end - st);
        acc += segSums[s] / fmaxf(cnt, 1.0f);
    }
    red[t] = acc;
    __syncthreads();
    for (int off = 128; off > 0; off >>= 1) {
        if (t < off) red[t] += red[t + off];
        __syncthreads();
    }
    if (t == 0) out[0] = red[0] * (1.0f / (float)NSEG) * STRENGTH;
}

extern "C" void kernel_launch(void* const* d_in, const int* in_sizes, int n_in,
                              void* d_out, int out_size, void* d_ws, size_t ws_size,
                              hipStream_t stream) {
    const float* x = (const float*)d_in[0];
    const float* y = (const float*)d_in[1];          // initial_sorted
    const int* seg = (const int*)d_in[2];            // segment_ids (sorted)
    int N = in_sizes[0];

    // pick bucket count per segment to fit workspace
    int B = 8192;
    while (B > 64) {
        size_t need = (size_t)N * 4 + 2ull * NSEG * B * 4 + 1024 * 4 + NSEG * 4 + 256;
        if (need <= ws_size) break;
        B >>= 1;
    }
    int M = NSEG * B;
    float scale = (float)B / 12.0f;

    char* ws = (char*)d_ws;
    float* sx      = (float*)ws;                         // N floats
    int*   counts  = (int*)(ws + (size_t)N * 4);         // M ints
    int*   cursor  = counts + M;                         // M ints (starts -> ends)
    int*   partials= cursor + M;                         // <=1024 ints
    float* segSums = (float*)(partials + 1024);          // NSEG floats

    hipMemsetAsync(counts, 0, (size_t)M * 4, stream);
    hipMemsetAsync(segSums, 0, NSEG * 4, stream);

    int nb = (M + 2047) / 2048;
    k_hist<<<2048, 256, 0, stream>>>(x, seg, counts, N, B, scale);
    k_scan_partial<<<nb, 256, 0, stream>>>(counts, partials, M);
    k_scan_carry<<<1, 1024, 0, stream>>>(partials, nb);
    k_scan_final<<<nb, 256, 0, stream>>>(counts, partials, cursor, M);
    k_scatter<<<2048, 256, 0, stream>>>(x, seg, cursor, sx, N, B, scale);
    k_emd<<<(N + 255) / 256, 256, 0, stream>>>(sx, y, seg, cursor, segSums, N, B, scale);
    k_final<<<1, 256, 0, stream>>>(segSums, cursor, (float*)d_out, B);
}